// Round 14
// baseline (450.192 us; speedup 1.0000x reference)
//
#include <hip/hip_runtime.h>
#include <hip/hip_bf16.h>
#include <math.h>

typedef unsigned short u16;
typedef unsigned int u32;
typedef __attribute__((ext_vector_type(8))) short short8;
typedef __attribute__((ext_vector_type(4))) float f32x4;

__device__ __forceinline__ float b2f(u16 u){ u32 i = ((u32)u)<<16; float f; __builtin_memcpy(&f,&i,4); return f; }
__device__ __forceinline__ u16 f2b(float f){ u32 i; __builtin_memcpy(&i,&f,4); u32 r=(i+0x7FFFu+((i>>16)&1u))>>16; return (u16)r; }
__device__ __forceinline__ int region(int h){ return h<21?0:(h<25?1:2); }

// bijective XCD-aware swizzle (m204) — validated for 256-thread blocks
__device__ __forceinline__ int xswz(int bid, int nwg){
  int q = nwg >> 3, r = nwg & 7;
  int xcd = bid & 7, loc = bid >> 3;
  int base = (xcd < r) ? xcd*(q+1) : r*(q+1) + (xcd-r)*q;
  return base + loc;
}

// ---------------- all-weights f32 -> bf16 (one dispatch) ----------------
__global__ __launch_bounds__(256) void wcvt_all(
    const float* __restrict__ w0, u16* __restrict__ o0,
    const float* __restrict__ w1, u16* __restrict__ o1,
    const float* __restrict__ w2, u16* __restrict__ o2,
    const float* __restrict__ w3, u16* __restrict__ o3)
{
  int b = blockIdx.x;
  const float* in; u16* out; int ofs;
  if (b < 432){ in=w0; out=o0; ofs=b; }
  else if (b < 576){ in=w1; out=o1; ofs=b-432; }
  else if (b < 1152){ in=w2; out=o2; ofs=b-576; }
  else { in=w3; out=o3; ofs=b-1152; }
  int i = (ofs*256 + threadIdx.x)*4;
  f32x4 v = *(const f32x4*)(in + i);
  u16 o[4];
  #pragma unroll
  for (int e=0;e<4;e++) o[e] = f2b(v[e]);
  *(u32*)(out+i) = (u32)o[0] | ((u32)o[1]<<16);
  *(u32*)(out+i+2) = (u32)o[2] | ((u32)o[3]<<16);
}

// ---------------- LN1 (f32 in) + roll + window partition -> bf16 ----------------
__global__ __launch_bounds__(256) void ln1_win(const float* __restrict__ x,
    const float* __restrict__ w, const float* __restrict__ bb, u16* __restrict__ out)
{
  int lane = threadIdx.x & 63;
  int t = blockIdx.x*4 + (threadIdx.x>>6);
  int win = t/49, n = t - win*49;
  int b = win>>4, wi = win&15;
  int r = n/7, c = n - r*7;
  int oh = (wi>>2)*7 + r + 3; if (oh>=28) oh -= 28;
  int ow = (wi&3)*7 + c + 3; if (ow>=28) ow -= 28;
  size_t src = ((size_t)b*784 + oh*28 + ow)*384;
  float v[6];
  #pragma unroll
  for (int p=0;p<3;p++){
    float2 d = *(const float2*)(x + src + 2*lane + 128*p);
    v[2*p] = d.x; v[2*p+1] = d.y;
  }
  float s=0.f, sq=0.f;
  #pragma unroll
  for (int e=0;e<6;e++){ s+=v[e]; sq+=v[e]*v[e]; }
  #pragma unroll
  for (int off=32; off>=1; off>>=1){ s+=__shfl_xor(s,off); sq+=__shfl_xor(sq,off); }
  float mean = s*(1.f/384.f);
  float rstd = rsqrtf(sq*(1.f/384.f)-mean*mean + 1e-5f);
  size_t dst = (size_t)t*384;
  #pragma unroll
  for (int p=0;p<3;p++){
    int col = 2*lane+128*p;
    float2 wd = *(const float2*)(w+col), bd = *(const float2*)(bb+col);
    float y0 = (v[2*p]-mean)*rstd*wd.x + bd.x;
    float y1 = (v[2*p+1]-mean)*rstd*wd.y + bd.y;
    *(u32*)(out + dst + col) = (u32)f2b(y0) | ((u32)f2b(y1)<<16);
  }
}

// ---------------- LN2, f32 input (fallback path) ----------------
__global__ __launch_bounds__(256) void ln2_k(const float* __restrict__ x2,
    const float* __restrict__ w, const float* __restrict__ bb, u16* __restrict__ out)
{
  int lane = threadIdx.x & 63;
  int t = blockIdx.x*4 + (threadIdx.x>>6);
  size_t base = (size_t)t*384;
  float v[6];
  #pragma unroll
  for (int p=0;p<3;p++){
    float2 d = *(const float2*)(x2 + base + 2*lane + 128*p);
    v[2*p] = d.x; v[2*p+1] = d.y;
  }
  float s=0.f, sq=0.f;
  #pragma unroll
  for (int e=0;e<6;e++){ s+=v[e]; sq+=v[e]*v[e]; }
  #pragma unroll
  for (int off=32; off>=1; off>>=1){ s+=__shfl_xor(s,off); sq+=__shfl_xor(sq,off); }
  float mean = s*(1.f/384.f);
  float rstd = rsqrtf(sq*(1.f/384.f)-mean*mean + 1e-5f);
  #pragma unroll
  for (int p=0;p<3;p++){
    int col = 2*lane+128*p;
    float2 wd = *(const float2*)(w+col), bd = *(const float2*)(bb+col);
    float y0 = (v[2*p]-mean)*rstd*wd.x + bd.x;
    float y1 = (v[2*p+1]-mean)*rstd*wd.y + bd.y;
    *(u32*)(out + base + col) = (u32)f2b(y0) | ((u32)f2b(y1)<<16);
  }
}

// ---------------- LN2, bf16 input (main path) ----------------
__global__ __launch_bounds__(256) void ln2_b(const u16* __restrict__ x2b,
    const float* __restrict__ w, const float* __restrict__ bb, u16* __restrict__ out)
{
  int lane = threadIdx.x & 63;
  int t = blockIdx.x*4 + (threadIdx.x>>6);
  size_t base = (size_t)t*384;
  float v[6];
  #pragma unroll
  for (int p=0;p<3;p++){
    u32 d = *(const u32*)(x2b + base + 2*lane + 128*p);
    v[2*p] = b2f((u16)(d&0xFFFFu)); v[2*p+1] = b2f((u16)(d>>16));
  }
  float s=0.f, sq=0.f;
  #pragma unroll
  for (int e=0;e<6;e++){ s+=v[e]; sq+=v[e]*v[e]; }
  #pragma unroll
  for (int off=32; off>=1; off>>=1){ s+=__shfl_xor(s,off); sq+=__shfl_xor(sq,off); }
  float mean = s*(1.f/384.f);
  float rstd = rsqrtf(sq*(1.f/384.f)-mean*mean + 1e-5f);
  #pragma unroll
  for (int p=0;p<3;p++){
    int col = 2*lane+128*p;
    float2 wd = *(const float2*)(w+col), bd = *(const float2*)(bb+col);
    float y0 = (v[2*p]-mean)*rstd*wd.x + bd.x;
    float y1 = (v[2*p+1]-mean)*rstd*wd.y + bd.y;
    *(u32*)(out + base + col) = (u32)f2b(y0) | ((u32)f2b(y1)<<16);
  }
}

// ---------------- MFMA attention: 1 wave per (window, head) ----------------
// v2: V staged transposed in LDS (chunk-XOR swizzle) -> vb = ds_read_b128;
//     O staged in (dead) P buffer -> coalesced 16B stores.
__global__ __launch_bounds__(256) void attn_mfma(const u16* __restrict__ qkv,
    const float* __restrict__ table, u16* __restrict__ out)
{
  __shared__ __align__(16) u16 P[4][4096];    // 8KB/wave: P 64x64 u16 (row-XOR swz); reused for O
  __shared__ __align__(16) u16 Vt[4][2048];   // 4KB/wave: V^T [d=32][tok=64], chunk-XOR swz
  __shared__ float bsh[4][224];
  int wv = threadIdx.x>>6, lane = threadIdx.x&63;
  int idx = blockIdx.x*4 + wv;
  int winl = idx/12, h = idx - winl*12;
  int wi = winl & 15;
  int g = lane>>4, q15 = lane&15;
  const float SCALE = 0.17677669529663687f;

  for (int e=lane; e<169; e+=64) bsh[wv][e] = table[e*12 + h];

  const u16* base = qkv + (size_t)winl*49*1152 + h*32;

  short8 qa[4], kb[4];
  #pragma unroll
  for (int t=0;t<4;t++){
    int tq = 16*t + q15; if (tq>48) tq = 48;
    qa[t] = *(const short8*)(base + (size_t)tq*1152 + g*8);
    kb[t] = *(const short8*)(base + (size_t)tq*1152 + 384 + g*8);
  }

  // ---- stage V -> Vt (transposed, chunk-XOR swizzled), coalesced 16B loads ----
  {
    char* Vw = (char*)&Vt[wv][0];
    int tokb = lane>>2, d0 = (lane&3)*8;
    #pragma unroll
    for (int shot=0; shot<4; ++shot){
      int tk = shot*16 + tokb;
      int tc = tk>48 ? 48 : tk;
      short8 v = *(const short8*)(base + (size_t)tc*1152 + 768 + d0);
      #pragma unroll
      for (int e=0;e<8;e++){
        int d = d0+e;
        int ch = (tk>>3) ^ (d&7);
        *(u16*)(Vw + d*128 + ch*16 + (tk&7)*2) = (u16)v[e];
      }
    }
  }

  f32x4 zero = {0.f,0.f,0.f,0.f};
  f32x4 s[4][4];
  #pragma unroll
  for (int ti=0;ti<4;ti++){
    #pragma unroll
    for (int tj=0;tj<4;tj++) s[ti][tj] = zero;
  }
  #pragma unroll
  for (int ti=0;ti<4;ti++){
    #pragma unroll
    for (int tj=0;tj<4;tj++)
      s[ti][tj] = __builtin_amdgcn_mfma_f32_16x16x32_bf16(qa[ti], kb[tj], s[ti][tj], 0,0,0);
  }

  int hb7 = (wi>>2)*7, wb7 = (wi&3)*7;
  int yj[4], xj[4], ridj[4]; bool kjok[4];
  #pragma unroll
  for (int tj=0;tj<4;tj++){
    int kj = 16*tj + q15;
    kjok[tj] = (kj < 49);
    int y = (kj*37)>>8; int xx = kj - y*7;
    yj[tj] = y; xj[tj] = xx;
    ridj[tj] = region(hb7+y)*3 + region(wb7+xx);
  }
  #pragma unroll
  for (int ti=0;ti<4;ti++){
    #pragma unroll
    for (int r=0;r<4;r++){
      int q = 16*ti + 4*g + r;
      int yi = (q*37)>>8, xi = q - yi*7;
      int ridi = region(hb7+yi)*3 + region(wb7+xi);
      int bb0 = (yi+6)*13 + xi + 6;
      #pragma unroll
      for (int tj=0;tj<4;tj++){
        float v;
        if (kjok[tj]){
          float bias = bsh[wv][bb0 - yj[tj]*13 - xj[tj]];
          v = s[ti][tj][r]*SCALE + bias + ((ridi==ridj[tj]) ? 0.f : -100.f);
        } else v = -1e30f;
        s[ti][tj][r] = v;
      }
    }
  }

  float inv[4][4];
  #pragma unroll
  for (int ti=0;ti<4;ti++){
    #pragma unroll
    for (int r=0;r<4;r++){
      float m = fmaxf(fmaxf(s[ti][0][r], s[ti][1][r]), fmaxf(s[ti][2][r], s[ti][3][r]));
      m = fmaxf(m, __shfl_xor(m,1));
      m = fmaxf(m, __shfl_xor(m,2));
      m = fmaxf(m, __shfl_xor(m,4));
      m = fmaxf(m, __shfl_xor(m,8));
      float sum = 0.f;
      #pragma unroll
      for (int tj=0;tj<4;tj++){
        float e = __expf(s[ti][tj][r] - m);
        s[ti][tj][r] = e; sum += e;
      }
      sum += __shfl_xor(sum,1);
      sum += __shfl_xor(sum,2);
      sum += __shfl_xor(sum,4);
      sum += __shfl_xor(sum,8);
      inv[ti][r] = 1.f/sum;
    }
  }

  u16* Pw = P[wv];
  #pragma unroll
  for (int ti=0;ti<4;ti++){
    #pragma unroll
    for (int r=0;r<4;r++){
      int q = 16*ti + 4*g + r;
      int swz = (q&7)<<4;
      #pragma unroll
      for (int tj=0;tj<4;tj++){
        int kj = 16*tj + q15;
        *(u16*)((char*)Pw + ((q*128 + kj*2) ^ swz)) = f2b(s[ti][tj][r]);
      }
    }
  }
  __syncthreads();

  f32x4 o[4][2];
  #pragma unroll
  for (int ti=0;ti<4;ti++){ o[ti][0]=zero; o[ti][1]=zero; }
  char* Vw = (char*)&Vt[wv][0];
  #pragma unroll
  for (int kk=0;kk<2;kk++){
    short8 pa[4];
    #pragma unroll
    for (int ti=0;ti<4;ti++){
      int qq = 16*ti + q15;
      pa[ti] = *(const short8*)((char*)Pw + ((qq*128 + kk*64 + g*16) ^ ((qq&7)<<4)));
    }
    #pragma unroll
    for (int tn=0;tn<2;tn++){
      short8 vb = *(const short8*)(Vw + (16*tn+q15)*128 + (((kk*4+g) ^ (q15&7))<<4));
      #pragma unroll
      for (int ti=0;ti<4;ti++)
        o[ti][tn] = __builtin_amdgcn_mfma_f32_16x16x32_bf16(pa[ti], vb, o[ti][tn], 0,0,0);
    }
  }

  // ---- O -> P-buffer (dead), then coalesced 16B stores ----
  char* Ob = (char*)Pw;   // 64 rows x 80B = 5120B <= 8KB
  #pragma unroll
  for (int ti=0;ti<4;ti++){
    #pragma unroll
    for (int r=0;r<4;r++){
      int tok = 16*ti + 4*g + r;
      float iv = inv[ti][r];
      #pragma unroll
      for (int tn=0;tn<2;tn++){
        int d = 16*tn + q15;
        *(u16*)(Ob + tok*80 + d*2) = f2b(o[ti][tn][r]*iv);
      }
    }
  }
  {
    int tokb = lane>>2, d0 = (lane&3)*8;
    #pragma unroll
    for (int shot=0; shot<4; ++shot){
      int tok = shot*16 + tokb;
      if (tok < 49){
        short8 ov = *(const short8*)(Ob + tok*80 + d0*2);
        *(short8*)(out + ((size_t)(winl*49+tok))*384 + h*32 + d0) = ov;
      }
    }
  }
}

// ---------------- GEMM: 128x128, BK=32, 3-buf, 1 barrier/phase (round-10 proven) ----------------
// EPI: 0 bias->bf16 (coalesced) ; 1 proj f32-x2 (fallback) ; 2 bias+GELU->bf16 (coalesced)
//      3 fc2 f32-x2 (fallback) ; 4 proj -> bf16 x2b (outb) ; 5 fc2: dout = v + b2f(outb)
#define STAGE(b, koff) do { \
  u16* _la = SH + (b)*8192 + wid*512; \
  u16* _lb = SH + (b)*8192 + 4096 + wid*512; \
  __builtin_amdgcn_global_load_lds((const __attribute__((address_space(1))) void*)(gA0+(koff)), \
      (__attribute__((address_space(3))) void*)_la, 16,0,0); \
  __builtin_amdgcn_global_load_lds((const __attribute__((address_space(1))) void*)(gA1+(koff)), \
      (__attribute__((address_space(3))) void*)(_la+2048), 16,0,0); \
  __builtin_amdgcn_global_load_lds((const __attribute__((address_space(1))) void*)(gB0+(koff)), \
      (__attribute__((address_space(3))) void*)_lb, 16,0,0); \
  __builtin_amdgcn_global_load_lds((const __attribute__((address_space(1))) void*)(gB1+(koff)), \
      (__attribute__((address_space(3))) void*)(_lb+2048), 16,0,0); \
} while(0)

#define COMPUTE(b) do { \
  const u16* _Ab = SH + (b)*8192; \
  const u16* _Bb = _Ab + 4096; \
  short8 af[4], bf[4]; \
  _Pragma("unroll") \
  for (int t_=0;t_<4;t_++){ \
    af[t_] = *(const short8*)(_Ab + aidx[t_]); \
    bf[t_] = *(const short8*)(_Bb + bidx[t_]); } \
  __builtin_amdgcn_s_setprio(1); \
  _Pragma("unroll") \
  for (int mi=0;mi<4;mi++){ \
    _Pragma("unroll") \
    for (int ni=0;ni<4;ni++){ \
      acc[mi][ni] = __builtin_amdgcn_mfma_f32_16x16x32_bf16(af[mi], bf[ni], acc[mi][ni], 0,0,0); } } \
  __builtin_amdgcn_s_setprio(0); \
} while(0)

template<int EPI>
__global__ __launch_bounds__(256) void gemm_nt(
    const u16* __restrict__ A, const u16* __restrict__ W,
    const float* __restrict__ bias, u16* __restrict__ outb,
    float* __restrict__ x2, const float* __restrict__ xin,
    float* __restrict__ dout, int rowofs, int N, int K, int ntn)
{
  __shared__ __align__(16) u16 SH[24576];   // 48 KB: 3 bufs x (A 8KB + B 8KB)
  int bid = xswz(blockIdx.x, gridDim.x);
  int tm = bid / ntn, tn = bid - tm*ntn;
  int tid = threadIdx.x, lane = tid&63, wid = tid>>6;
  int wm = wid>>1, wn = wid&1;
  int fr = lane&15, fc = lane>>4;

  int s0 = wid*1024 + lane*16;
  int row0 = s0>>6;  int cl0 = ((s0>>4)&3) ^ ((row0>>1)&3);
  int s1b = s0 + 4096;
  int row1 = s1b>>6; int cl1 = ((s1b>>4)&3) ^ ((row1>>1)&3);
  const u16* gA0 = A + (size_t)(tm*128 + row0)*K + cl0*8;
  const u16* gA1 = A + (size_t)(tm*128 + row1)*K + cl1*8;
  const u16* gB0 = W + (size_t)(tn*128 + row0)*K + cl0*8;
  const u16* gB1 = W + (size_t)(tn*128 + row1)*K + cl1*8;

  f32x4 zero = {0.f,0.f,0.f,0.f};
  f32x4 acc[4][4];
  #pragma unroll
  for (int a=0;a<4;a++){
    #pragma unroll
    for (int b=0;b<4;b++) acc[a][b] = zero;
  }
  int aidx[4], bidx[4];
  #pragma unroll
  for (int t_=0;t_<4;t_++){
    int ra = wm*64 + t_*16 + fr;
    aidx[t_] = ra*32 + ((fc ^ ((ra>>1)&3))*8);
    int rb = wn*64 + t_*16 + fr;
    bidx[t_] = rb*32 + ((fc ^ ((rb>>1)&3))*8);
  }

  // 3-buf, single barrier per phase (round-10 schedule)
  int NT = K>>5;
  STAGE(0, 0);
  STAGE(1, 32);
  int b = 0;
  for (int t=0; t<NT; ++t){
    if (t < NT-1)  asm volatile("s_waitcnt vmcnt(4)" ::: "memory");
    else           asm volatile("s_waitcnt vmcnt(0)" ::: "memory");
    __builtin_amdgcn_s_barrier();
    __builtin_amdgcn_sched_barrier(0);
    int nb = b+2; if (nb>=3) nb-=3;
    if (t+2 < NT) STAGE(nb, (t+2)*32);
    COMPUTE(b);
    if (++b == 3) b = 0;
  }

  int colbase = tn*128 + wn*64;
  int rowbase = tm*128 + wm*64;

  if (EPI==0 || EPI==2){
    __builtin_amdgcn_s_barrier();
    u16* ep = SH + wid*4096;
    #pragma unroll
    for (int ni=0;ni<4;ni++){
      float bv = bias[colbase + ni*16 + fr];
      #pragma unroll
      for (int mi=0;mi<4;mi++){
        #pragma unroll
        for (int rr=0;rr<4;rr++){
          float v = acc[mi][ni][rr] + bv;
          if (EPI==2){
            float u2 = -1.5957691216057308f*(v + 0.044715f*v*v*v);
            v = v / (1.f + __expf(u2));
          }
          ep[(mi*16 + fc*4 + rr)*64 + ni*16 + fr] = f2b(v);
        }
      }
    }
    int half = lane>>5, c2 = (lane&31)*2;
    #pragma unroll
    for (int it=0; it<32; ++it){
      int lrow = it*2 + half;
      u32 v = *(const u32*)(ep + lrow*64 + c2);
      *(u32*)(outb + (size_t)(rowbase + lrow)*N + colbase + c2) = v;
    }
  } else {
    #pragma unroll
    for (int ni=0;ni<4;ni++){
      int col = colbase + ni*16 + fr;
      float bv = bias[col];
      #pragma unroll
      for (int mi=0;mi<4;mi++){
        #pragma unroll
        for (int rr=0;rr<4;rr++){
          int row = rowbase + mi*16 + fc*4 + rr;
          float v = acc[mi][ni][rr] + bv;
          if (EPI==1 || EPI==4){
            int grow = rowofs + row;
            int win = grow/49, n = grow - win*49;
            int bb = win>>4, wi = win&15;
            int hh = (wi>>2)*7 + n/7 + 3; if (hh>=28) hh -= 28;
            int ww = (wi&3)*7 + (n - (n/7)*7) + 3; if (ww>=28) ww -= 28;
            size_t ti = ((size_t)bb*784 + hh*28 + ww)*384 + col;
            if (EPI==1) x2[ti] = v + xin[ti];
            else        outb[ti] = f2b(v + xin[ti]);
          } else if (EPI==3){
            size_t ti = (size_t)row*N + col;
            dout[ti] = v + x2[ti];
          } else {  // EPI==5
            size_t ti = (size_t)row*N + col;
            dout[ti] = v + b2f(outb[ti]);
          }
        }
      }
    }
  }
}

extern "C" void kernel_launch(void* const* d_in, const int* in_sizes, int n_in,
                              void* d_out, int out_size, void* d_ws, size_t ws_size,
                              hipStream_t stream)
{
  const float* x     = (const float*)d_in[0];
  const float* n1w   = (const float*)d_in[2];
  const float* n1b   = (const float*)d_in[3];
  const float* qkvw  = (const float*)d_in[4];
  const float* qkvb  = (const float*)d_in[5];
  const float* relt  = (const float*)d_in[6];
  const float* projw = (const float*)d_in[7];
  const float* projb = (const float*)d_in[8];
  const float* n2w   = (const float*)d_in[9];
  const float* n2b   = (const float*)d_in[10];
  const float* fc1w  = (const float*)d_in[11];
  const float* fc1b  = (const float*)d_in[12];
  const float* fc2w  = (const float*)d_in[13];
  const float* fc2b  = (const float*)d_in[14];

  char* ws = (char*)d_ws;
  float* outf = (float*)d_out;

  if (ws_size >= 196214784){
    u16* B0    = (u16*)ws;
    u16* x2b   = (u16*)(ws + 38535168);
    u16* qkvc  = (u16*)(ws + 38535168);
    u16* fc1c  = (u16*)(ws + 77070336);
    u16* attnc = (u16*)(ws + 154140672);
    char* wb   = ws + 192675840;
    u16* wq = (u16*)(wb); u16* wp = (u16*)(wb + 884736);
    u16* w1 = (u16*)(wb + 1179648); u16* w2 = (u16*)(wb + 2359296);

    wcvt_all<<<1728,256,0,stream>>>(qkvw,wq, projw,wp, fc1w,w1, fc2w,w2);
    ln1_win<<<12544,256,0,stream>>>(x, n1w, n1b, B0);
    gemm_nt<0><<<392*9,256,0,stream>>>(B0, wq, qkvb, qkvc, nullptr, nullptr, nullptr, 0, 1152,384,9);
    attn_mfma<<<3072,256,0,stream>>>(qkvc, relt, attnc);
    gemm_nt<4><<<392*3,256,0,stream>>>(attnc, wp, projb, x2b, nullptr, x, nullptr, 0, 384,384,3);
    ln2_b<<<12544,256,0,stream>>>(x2b, n2w, n2b, B0);
    for (int c=0; c<2; ++c){
      const u16* a1 = B0 + (size_t)c*25088*384;
      gemm_nt<2><<<196*12,256,0,stream>>>(a1, w1, fc1b, fc1c, nullptr, nullptr, nullptr, 0, 1536,384,12);
      gemm_nt<5><<<196*3 ,256,0,stream>>>(fc1c, w2, fc2b, x2b + (size_t)c*25088*384, nullptr, nullptr,
                                          outf + (size_t)c*25088*384, 0, 384,1536,3);
    }
  } else {
    int nc = (ws_size >= 119144448) ? 2 : 4;
    int Mc = 50176/nc;
    u16* B0    = (u16*)ws;
    u16* qkvc  = (u16*)(ws + 38535168);
    u16* attnc = qkvc + (size_t)Mc*1152;
    u16* fc1c  = qkvc;
    char* wb   = ws + 38535168 + (size_t)Mc*3072;
    u16* wq = (u16*)(wb); u16* wp = (u16*)(wb + 884736);
    u16* w1 = (u16*)(wb + 1179648); u16* w2 = (u16*)(wb + 2359296);

    wcvt_all<<<1728,256,0,stream>>>(qkvw,wq, projw,wp, fc1w,w1, fc2w,w2);
    ln1_win<<<12544,256,0,stream>>>(x, n1w, n1b, B0);
    int mt = Mc/128;
    for (int c=0; c<nc; ++c){
      const u16* a0 = B0 + (size_t)c*Mc*384;
      gemm_nt<0><<<mt*9,256,0,stream>>>(a0, wq, qkvb, qkvc, nullptr, nullptr, nullptr, 0, 1152,384,9);
      attn_mfma<<<Mc/49*3,256,0,stream>>>(qkvc, relt, attnc);
      gemm_nt<1><<<mt*3,256,0,stream>>>(attnc, wp, projb, nullptr, outf, x, nullptr, c*Mc, 384,384,3);
    }
    ln2_k<<<12544,256,0,stream>>>(outf, n2w, n2b, B0);
    for (int c=0; c<nc; ++c){
      const u16* a1 = B0 + (size_t)c*Mc*384;
      float* oc = outf + (size_t)c*Mc*384;
      gemm_nt<2><<<mt*12,256,0,stream>>>(a1, w1, fc1b, fc1c, nullptr, nullptr, nullptr, 0, 1536,384,12);
      gemm_nt<3><<<mt*3 ,256,0,stream>>>(fc1c, w2, fc2b, nullptr, oc, nullptr, oc, 0, 384,1536,3);
    }
  }
}

// Round 15
// 442.001 us; speedup vs baseline: 1.0185x; 1.0185x over previous
//
#include <hip/hip_runtime.h>
#include <hip/hip_bf16.h>
#include <math.h>

typedef unsigned short u16;
typedef unsigned int u32;
typedef __attribute__((ext_vector_type(8))) short short8;
typedef __attribute__((ext_vector_type(4))) float f32x4;

__device__ __forceinline__ float b2f(u16 u){ u32 i = ((u32)u)<<16; float f; __builtin_memcpy(&f,&i,4); return f; }
__device__ __forceinline__ u16 f2b(float f){ u32 i; __builtin_memcpy(&i,&f,4); u32 r=(i+0x7FFFu+((i>>16)&1u))>>16; return (u16)r; }
__device__ __forceinline__ int region(int h){ return h<21?0:(h<25?1:2); }

// bijective XCD-aware swizzle (m204) — validated for 256-thread blocks
__device__ __forceinline__ int xswz(int bid, int nwg){
  int q = nwg >> 3, r = nwg & 7;
  int xcd = bid & 7, loc = bid >> 3;
  int base = (xcd < r) ? xcd*(q+1) : r*(q+1) + (xcd-r)*q;
  return base + loc;
}

// ---------------- all-weights f32 -> bf16 (one dispatch) ----------------
__global__ __launch_bounds__(256) void wcvt_all(
    const float* __restrict__ w0, u16* __restrict__ o0,
    const float* __restrict__ w1, u16* __restrict__ o1,
    const float* __restrict__ w2, u16* __restrict__ o2,
    const float* __restrict__ w3, u16* __restrict__ o3)
{
  int b = blockIdx.x;
  const float* in; u16* out; int ofs;
  if (b < 432){ in=w0; out=o0; ofs=b; }
  else if (b < 576){ in=w1; out=o1; ofs=b-432; }
  else if (b < 1152){ in=w2; out=o2; ofs=b-576; }
  else { in=w3; out=o3; ofs=b-1152; }
  int i = (ofs*256 + threadIdx.x)*4;
  f32x4 v = *(const f32x4*)(in + i);
  u16 o[4];
  #pragma unroll
  for (int e=0;e<4;e++) o[e] = f2b(v[e]);
  *(u32*)(out+i) = (u32)o[0] | ((u32)o[1]<<16);
  *(u32*)(out+i+2) = (u32)o[2] | ((u32)o[3]<<16);
}

// ---------------- LN1 (f32 in) + roll + window partition -> bf16 ----------------
__global__ __launch_bounds__(256) void ln1_win(const float* __restrict__ x,
    const float* __restrict__ w, const float* __restrict__ bb, u16* __restrict__ out)
{
  int lane = threadIdx.x & 63;
  int t = blockIdx.x*4 + (threadIdx.x>>6);
  int win = t/49, n = t - win*49;
  int b = win>>4, wi = win&15;
  int r = n/7, c = n - r*7;
  int oh = (wi>>2)*7 + r + 3; if (oh>=28) oh -= 28;
  int ow = (wi&3)*7 + c + 3; if (ow>=28) ow -= 28;
  size_t src = ((size_t)b*784 + oh*28 + ow)*384;
  float v[6];
  #pragma unroll
  for (int p=0;p<3;p++){
    float2 d = *(const float2*)(x + src + 2*lane + 128*p);
    v[2*p] = d.x; v[2*p+1] = d.y;
  }
  float s=0.f, sq=0.f;
  #pragma unroll
  for (int e=0;e<6;e++){ s+=v[e]; sq+=v[e]*v[e]; }
  #pragma unroll
  for (int off=32; off>=1; off>>=1){ s+=__shfl_xor(s,off); sq+=__shfl_xor(sq,off); }
  float mean = s*(1.f/384.f);
  float rstd = rsqrtf(sq*(1.f/384.f)-mean*mean + 1e-5f);
  size_t dst = (size_t)t*384;
  #pragma unroll
  for (int p=0;p<3;p++){
    int col = 2*lane+128*p;
    float2 wd = *(const float2*)(w+col), bd = *(const float2*)(bb+col);
    float y0 = (v[2*p]-mean)*rstd*wd.x + bd.x;
    float y1 = (v[2*p+1]-mean)*rstd*wd.y + bd.y;
    *(u32*)(out + dst + col) = (u32)f2b(y0) | ((u32)f2b(y1)<<16);
  }
}

// ---------------- LN2, f32 input (fallback path) ----------------
__global__ __launch_bounds__(256) void ln2_k(const float* __restrict__ x2,
    const float* __restrict__ w, const float* __restrict__ bb, u16* __restrict__ out)
{
  int lane = threadIdx.x & 63;
  int t = blockIdx.x*4 + (threadIdx.x>>6);
  size_t base = (size_t)t*384;
  float v[6];
  #pragma unroll
  for (int p=0;p<3;p++){
    float2 d = *(const float2*)(x2 + base + 2*lane + 128*p);
    v[2*p] = d.x; v[2*p+1] = d.y;
  }
  float s=0.f, sq=0.f;
  #pragma unroll
  for (int e=0;e<6;e++){ s+=v[e]; sq+=v[e]*v[e]; }
  #pragma unroll
  for (int off=32; off>=1; off>>=1){ s+=__shfl_xor(s,off); sq+=__shfl_xor(sq,off); }
  float mean = s*(1.f/384.f);
  float rstd = rsqrtf(sq*(1.f/384.f)-mean*mean + 1e-5f);
  #pragma unroll
  for (int p=0;p<3;p++){
    int col = 2*lane+128*p;
    float2 wd = *(const float2*)(w+col), bd = *(const float2*)(bb+col);
    float y0 = (v[2*p]-mean)*rstd*wd.x + bd.x;
    float y1 = (v[2*p+1]-mean)*rstd*wd.y + bd.y;
    *(u32*)(out + base + col) = (u32)f2b(y0) | ((u32)f2b(y1)<<16);
  }
}

// ---------------- LN2, bf16 input (main path) ----------------
__global__ __launch_bounds__(256) void ln2_b(const u16* __restrict__ x2b,
    const float* __restrict__ w, const float* __restrict__ bb, u16* __restrict__ out)
{
  int lane = threadIdx.x & 63;
  int t = blockIdx.x*4 + (threadIdx.x>>6);
  size_t base = (size_t)t*384;
  float v[6];
  #pragma unroll
  for (int p=0;p<3;p++){
    u32 d = *(const u32*)(x2b + base + 2*lane + 128*p);
    v[2*p] = b2f((u16)(d&0xFFFFu)); v[2*p+1] = b2f((u16)(d>>16));
  }
  float s=0.f, sq=0.f;
  #pragma unroll
  for (int e=0;e<6;e++){ s+=v[e]; sq+=v[e]*v[e]; }
  #pragma unroll
  for (int off=32; off>=1; off>>=1){ s+=__shfl_xor(s,off); sq+=__shfl_xor(sq,off); }
  float mean = s*(1.f/384.f);
  float rstd = rsqrtf(sq*(1.f/384.f)-mean*mean + 1e-5f);
  #pragma unroll
  for (int p=0;p<3;p++){
    int col = 2*lane+128*p;
    float2 wd = *(const float2*)(w+col), bd = *(const float2*)(bb+col);
    float y0 = (v[2*p]-mean)*rstd*wd.x + bd.x;
    float y1 = (v[2*p+1]-mean)*rstd*wd.y + bd.y;
    *(u32*)(out + base + col) = (u32)f2b(y0) | ((u32)f2b(y1)<<16);
  }
}

// ---------------- MFMA attention: 1 wave per (window, head) ----------------
// round-13 base + (a) coalesced O epilogue via dead P buffer, (b) no max-sub
// (scores bounded; mask/pad exp -> 0), (c) s_setprio around MFMA clusters.
__global__ __launch_bounds__(256) void attn_mfma(const u16* __restrict__ qkv,
    const float* __restrict__ table, u16* __restrict__ out)
{
  __shared__ __align__(16) u16 P[4][4096];
  __shared__ float bsh[4][224];
  int wv = threadIdx.x>>6, lane = threadIdx.x&63;
  int idx = blockIdx.x*4 + wv;
  int winl = idx/12, h = idx - winl*12;
  int wi = winl & 15;
  int g = lane>>4, q15 = lane&15;
  const float SCALE = 0.17677669529663687f;

  for (int e=lane; e<169; e+=64) bsh[wv][e] = table[e*12 + h];

  const u16* base = qkv + (size_t)winl*49*1152 + h*32;

  short8 qa[4], kb[4];
  #pragma unroll
  for (int t=0;t<4;t++){
    int tq = 16*t + q15; if (tq>48) tq = 48;
    qa[t] = *(const short8*)(base + (size_t)tq*1152 + g*8);
    kb[t] = *(const short8*)(base + (size_t)tq*1152 + 384 + g*8);
  }
  f32x4 zero = {0.f,0.f,0.f,0.f};
  f32x4 s[4][4];
  #pragma unroll
  for (int ti=0;ti<4;ti++){
    #pragma unroll
    for (int tj=0;tj<4;tj++) s[ti][tj] = zero;
  }
  __builtin_amdgcn_s_setprio(1);
  #pragma unroll
  for (int ti=0;ti<4;ti++){
    #pragma unroll
    for (int tj=0;tj<4;tj++)
      s[ti][tj] = __builtin_amdgcn_mfma_f32_16x16x32_bf16(qa[ti], kb[tj], s[ti][tj], 0,0,0);
  }
  __builtin_amdgcn_s_setprio(0);

  int hb7 = (wi>>2)*7, wb7 = (wi&3)*7;
  int yj[4], xj[4], ridj[4]; bool kjok[4];
  #pragma unroll
  for (int tj=0;tj<4;tj++){
    int kj = 16*tj + q15;
    kjok[tj] = (kj < 49);
    int y = (kj*37)>>8; int xx = kj - y*7;
    yj[tj] = y; xj[tj] = xx;
    ridj[tj] = region(hb7+y)*3 + region(wb7+xx);
  }
  #pragma unroll
  for (int ti=0;ti<4;ti++){
    #pragma unroll
    for (int r=0;r<4;r++){
      int q = 16*ti + 4*g + r;
      int yi = (q*37)>>8, xi = q - yi*7;
      int ridi = region(hb7+yi)*3 + region(wb7+xi);
      int bb0 = (yi+6)*13 + xi + 6;
      #pragma unroll
      for (int tj=0;tj<4;tj++){
        float v;
        if (kjok[tj]){
          float bias = bsh[wv][bb0 - yj[tj]*13 - xj[tj]];
          v = s[ti][tj][r]*SCALE + bias + ((ridi==ridj[tj]) ? 0.f : -100.f);
        } else v = -1e30f;
        s[ti][tj][r] = v;
      }
    }
  }

  // softmax without max-shift: scores bounded (~|s|<=2 for real rows; masked -100 -> exp ~0,
  // padded -1e30 -> exp = 0). Row sum >= exp(s_self) > 0.
  float inv[4][4];
  #pragma unroll
  for (int ti=0;ti<4;ti++){
    #pragma unroll
    for (int r=0;r<4;r++){
      float sum = 0.f;
      #pragma unroll
      for (int tj=0;tj<4;tj++){
        float e = __expf(s[ti][tj][r]);
        s[ti][tj][r] = e; sum += e;
      }
      sum += __shfl_xor(sum,1);
      sum += __shfl_xor(sum,2);
      sum += __shfl_xor(sum,4);
      sum += __shfl_xor(sum,8);
      inv[ti][r] = 1.f/sum;
    }
  }

  u16* Pw = P[wv];
  #pragma unroll
  for (int ti=0;ti<4;ti++){
    #pragma unroll
    for (int r=0;r<4;r++){
      int q = 16*ti + 4*g + r;
      int swz = (q&7)<<4;
      #pragma unroll
      for (int tj=0;tj<4;tj++){
        int kj = 16*tj + q15;
        *(u16*)((char*)Pw + ((q*128 + kj*2) ^ swz)) = f2b(s[ti][tj][r]);
      }
    }
  }
  __syncthreads();

  f32x4 o[4][2];
  #pragma unroll
  for (int ti=0;ti<4;ti++){ o[ti][0]=zero; o[ti][1]=zero; }
  #pragma unroll
  for (int kk=0;kk<2;kk++){
    short8 pa[4];
    #pragma unroll
    for (int ti=0;ti<4;ti++){
      int qq = 16*ti + q15;
      pa[ti] = *(const short8*)((char*)Pw + ((qq*128 + kk*64 + g*16) ^ ((qq&7)<<4)));
    }
    #pragma unroll
    for (int tn=0;tn<2;tn++){
      short8 vb;
      #pragma unroll
      for (int e=0;e<8;e++){
        int tok = kk*32 + g*8 + e; if (tok>48) tok = 48;
        vb[e] = *(const short*)(base + (size_t)tok*1152 + 768 + 16*tn + q15);
      }
      __builtin_amdgcn_s_setprio(1);
      #pragma unroll
      for (int ti=0;ti<4;ti++)
        o[ti][tn] = __builtin_amdgcn_mfma_f32_16x16x32_bf16(pa[ti], vb, o[ti][tn], 0,0,0);
      __builtin_amdgcn_s_setprio(0);
    }
  }

  // ---- O -> dead P buffer (80B-stride rows), then coalesced 16B stores ----
  char* Ob = (char*)Pw;   // 64 rows x 80 B = 5120 B <= 8 KB; P dead after pa reads
  #pragma unroll
  for (int ti=0;ti<4;ti++){
    #pragma unroll
    for (int r=0;r<4;r++){
      int tok = 16*ti + 4*g + r;
      float iv = inv[ti][r];
      *(u16*)(Ob + tok*80 + q15*2)      = f2b(o[ti][0][r]*iv);
      *(u16*)(Ob + tok*80 + 32 + q15*2) = f2b(o[ti][1][r]*iv);
    }
  }
  {
    int tokb = lane>>2, d0 = (lane&3)*8;
    #pragma unroll
    for (int shot=0; shot<4; ++shot){
      int tok = shot*16 + tokb;
      if (tok < 49){
        short8 ov = *(const short8*)(Ob + tok*80 + d0*2);
        *(short8*)(out + ((size_t)(winl*49+tok))*384 + h*32 + d0) = ov;
      }
    }
  }
}

// ---------------- GEMM: 128x128, BK=32, 3-buf, 1 barrier/phase (round-10 proven) ----------------
// EPI: 0 bias->bf16 (coalesced) ; 1 proj f32-x2 (fallback) ; 2 bias+GELU->bf16 (coalesced)
//      3 fc2 f32-x2 (fallback) ; 4 proj -> bf16 x2b (outb) ; 5 fc2: dout = v + b2f(outb)
#define STAGE(b, koff) do { \
  u16* _la = SH + (b)*8192 + wid*512; \
  u16* _lb = SH + (b)*8192 + 4096 + wid*512; \
  __builtin_amdgcn_global_load_lds((const __attribute__((address_space(1))) void*)(gA0+(koff)), \
      (__attribute__((address_space(3))) void*)_la, 16,0,0); \
  __builtin_amdgcn_global_load_lds((const __attribute__((address_space(1))) void*)(gA1+(koff)), \
      (__attribute__((address_space(3))) void*)(_la+2048), 16,0,0); \
  __builtin_amdgcn_global_load_lds((const __attribute__((address_space(1))) void*)(gB0+(koff)), \
      (__attribute__((address_space(3))) void*)_lb, 16,0,0); \
  __builtin_amdgcn_global_load_lds((const __attribute__((address_space(1))) void*)(gB1+(koff)), \
      (__attribute__((address_space(3))) void*)(_lb+2048), 16,0,0); \
} while(0)

#define COMPUTE(b) do { \
  const u16* _Ab = SH + (b)*8192; \
  const u16* _Bb = _Ab + 4096; \
  short8 af[4], bf[4]; \
  _Pragma("unroll") \
  for (int t_=0;t_<4;t_++){ \
    af[t_] = *(const short8*)(_Ab + aidx[t_]); \
    bf[t_] = *(const short8*)(_Bb + bidx[t_]); } \
  __builtin_amdgcn_s_setprio(1); \
  _Pragma("unroll") \
  for (int mi=0;mi<4;mi++){ \
    _Pragma("unroll") \
    for (int ni=0;ni<4;ni++){ \
      acc[mi][ni] = __builtin_amdgcn_mfma_f32_16x16x32_bf16(af[mi], bf[ni], acc[mi][ni], 0,0,0); } } \
  __builtin_amdgcn_s_setprio(0); \
} while(0)

template<int EPI>
__global__ __launch_bounds__(256) void gemm_nt(
    const u16* __restrict__ A, const u16* __restrict__ W,
    const float* __restrict__ bias, u16* __restrict__ outb,
    float* __restrict__ x2, const float* __restrict__ xin,
    float* __restrict__ dout, int rowofs, int N, int K, int ntn)
{
  __shared__ __align__(16) u16 SH[24576];   // 48 KB: 3 bufs x (A 8KB + B 8KB)
  int bid = xswz(blockIdx.x, gridDim.x);
  int tm = bid / ntn, tn = bid - tm*ntn;
  int tid = threadIdx.x, lane = tid&63, wid = tid>>6;
  int wm = wid>>1, wn = wid&1;
  int fr = lane&15, fc = lane>>4;

  int s0 = wid*1024 + lane*16;
  int row0 = s0>>6;  int cl0 = ((s0>>4)&3) ^ ((row0>>1)&3);
  int s1b = s0 + 4096;
  int row1 = s1b>>6; int cl1 = ((s1b>>4)&3) ^ ((row1>>1)&3);
  const u16* gA0 = A + (size_t)(tm*128 + row0)*K + cl0*8;
  const u16* gA1 = A + (size_t)(tm*128 + row1)*K + cl1*8;
  const u16* gB0 = W + (size_t)(tn*128 + row0)*K + cl0*8;
  const u16* gB1 = W + (size_t)(tn*128 + row1)*K + cl1*8;

  f32x4 zero = {0.f,0.f,0.f,0.f};
  f32x4 acc[4][4];
  #pragma unroll
  for (int a=0;a<4;a++){
    #pragma unroll
    for (int b=0;b<4;b++) acc[a][b] = zero;
  }
  int aidx[4], bidx[4];
  #pragma unroll
  for (int t_=0;t_<4;t_++){
    int ra = wm*64 + t_*16 + fr;
    aidx[t_] = ra*32 + ((fc ^ ((ra>>1)&3))*8);
    int rb = wn*64 + t_*16 + fr;
    bidx[t_] = rb*32 + ((fc ^ ((rb>>1)&3))*8);
  }

  // 3-buf, single barrier per phase (round-10 schedule)
  int NT = K>>5;
  STAGE(0, 0);
  STAGE(1, 32);
  int b = 0;
  for (int t=0; t<NT; ++t){
    if (t < NT-1)  asm volatile("s_waitcnt vmcnt(4)" ::: "memory");
    else           asm volatile("s_waitcnt vmcnt(0)" ::: "memory");
    __builtin_amdgcn_s_barrier();
    __builtin_amdgcn_sched_barrier(0);
    int nb = b+2; if (nb>=3) nb-=3;
    if (t+2 < NT) STAGE(nb, (t+2)*32);
    COMPUTE(b);
    if (++b == 3) b = 0;
  }

  int colbase = tn*128 + wn*64;
  int rowbase = tm*128 + wm*64;

  if (EPI==0 || EPI==2){
    __builtin_amdgcn_s_barrier();
    u16* ep = SH + wid*4096;
    #pragma unroll
    for (int ni=0;ni<4;ni++){
      float bv = bias[colbase + ni*16 + fr];
      #pragma unroll
      for (int mi=0;mi<4;mi++){
        #pragma unroll
        for (int rr=0;rr<4;rr++){
          float v = acc[mi][ni][rr] + bv;
          if (EPI==2){
            float u2 = -1.5957691216057308f*(v + 0.044715f*v*v*v);
            v = v / (1.f + __expf(u2));
          }
          ep[(mi*16 + fc*4 + rr)*64 + ni*16 + fr] = f2b(v);
        }
      }
    }
    int half = lane>>5, c2 = (lane&31)*2;
    #pragma unroll
    for (int it=0; it<32; ++it){
      int lrow = it*2 + half;
      u32 v = *(const u32*)(ep + lrow*64 + c2);
      *(u32*)(outb + (size_t)(rowbase + lrow)*N + colbase + c2) = v;
    }
  } else {
    #pragma unroll
    for (int ni=0;ni<4;ni++){
      int col = colbase + ni*16 + fr;
      float bv = bias[col];
      #pragma unroll
      for (int mi=0;mi<4;mi++){
        #pragma unroll
        for (int rr=0;rr<4;rr++){
          int row = rowbase + mi*16 + fc*4 + rr;
          float v = acc[mi][ni][rr] + bv;
          if (EPI==1 || EPI==4){
            int grow = rowofs + row;
            int win = grow/49, n = grow - win*49;
            int bb = win>>4, wi = win&15;
            int hh = (wi>>2)*7 + n/7 + 3; if (hh>=28) hh -= 28;
            int ww = (wi&3)*7 + (n - (n/7)*7) + 3; if (ww>=28) ww -= 28;
            size_t ti = ((size_t)bb*784 + hh*28 + ww)*384 + col;
            if (EPI==1) x2[ti] = v + xin[ti];
            else        outb[ti] = f2b(v + xin[ti]);
          } else if (EPI==3){
            size_t ti = (size_t)row*N + col;
            dout[ti] = v + x2[ti];
          } else {  // EPI==5
            size_t ti = (size_t)row*N + col;
            dout[ti] = v + b2f(outb[ti]);
          }
        }
      }
    }
  }
}

extern "C" void kernel_launch(void* const* d_in, const int* in_sizes, int n_in,
                              void* d_out, int out_size, void* d_ws, size_t ws_size,
                              hipStream_t stream)
{
  const float* x     = (const float*)d_in[0];
  const float* n1w   = (const float*)d_in[2];
  const float* n1b   = (const float*)d_in[3];
  const float* qkvw  = (const float*)d_in[4];
  const float* qkvb  = (const float*)d_in[5];
  const float* relt  = (const float*)d_in[6];
  const float* projw = (const float*)d_in[7];
  const float* projb = (const float*)d_in[8];
  const float* n2w   = (const float*)d_in[9];
  const float* n2b   = (const float*)d_in[10];
  const float* fc1w  = (const float*)d_in[11];
  const float* fc1b  = (const float*)d_in[12];
  const float* fc2w  = (const float*)d_in[13];
  const float* fc2b  = (const float*)d_in[14];

  char* ws = (char*)d_ws;
  float* outf = (float*)d_out;

  if (ws_size >= 196214784){
    u16* B0    = (u16*)ws;
    u16* x2b   = (u16*)(ws + 38535168);
    u16* qkvc  = (u16*)(ws + 38535168);
    u16* fc1c  = (u16*)(ws + 77070336);
    u16* attnc = (u16*)(ws + 154140672);
    char* wb   = ws + 192675840;
    u16* wq = (u16*)(wb); u16* wp = (u16*)(wb + 884736);
    u16* w1 = (u16*)(wb + 1179648); u16* w2 = (u16*)(wb + 2359296);

    wcvt_all<<<1728,256,0,stream>>>(qkvw,wq, projw,wp, fc1w,w1, fc2w,w2);
    ln1_win<<<12544,256,0,stream>>>(x, n1w, n1b, B0);
    gemm_nt<0><<<392*9,256,0,stream>>>(B0, wq, qkvb, qkvc, nullptr, nullptr, nullptr, 0, 1152,384,9);
    attn_mfma<<<3072,256,0,stream>>>(qkvc, relt, attnc);
    gemm_nt<4><<<392*3,256,0,stream>>>(attnc, wp, projb, x2b, nullptr, x, nullptr, 0, 384,384,3);
    ln2_b<<<12544,256,0,stream>>>(x2b, n2w, n2b, B0);
    for (int c=0; c<2; ++c){
      const u16* a1 = B0 + (size_t)c*25088*384;
      gemm_nt<2><<<196*12,256,0,stream>>>(a1, w1, fc1b, fc1c, nullptr, nullptr, nullptr, 0, 1536,384,12);
      gemm_nt<5><<<196*3 ,256,0,stream>>>(fc1c, w2, fc2b, x2b + (size_t)c*25088*384, nullptr, nullptr,
                                          outf + (size_t)c*25088*384, 0, 384,1536,3);
    }
  } else {
    int nc = (ws_size >= 119144448) ? 2 : 4;
    int Mc = 50176/nc;
    u16* B0    = (u16*)ws;
    u16* qkvc  = (u16*)(ws + 38535168);
    u16* attnc = qkvc + (size_t)Mc*1152;
    u16* fc1c  = qkvc;
    char* wb   = ws + 38535168 + (size_t)Mc*3072;
    u16* wq = (u16*)(wb); u16* wp = (u16*)(wb + 884736);
    u16* w1 = (u16*)(wb + 1179648); u16* w2 = (u16*)(wb + 2359296);

    wcvt_all<<<1728,256,0,stream>>>(qkvw,wq, projw,wp, fc1w,w1, fc2w,w2);
    ln1_win<<<12544,256,0,stream>>>(x, n1w, n1b, B0);
    int mt = Mc/128;
    for (int c=0; c<nc; ++c){
      const u16* a0 = B0 + (size_t)c*Mc*384;
      gemm_nt<0><<<mt*9,256,0,stream>>>(a0, wq, qkvb, qkvc, nullptr, nullptr, nullptr, 0, 1152,384,9);
      attn_mfma<<<Mc/49*3,256,0,stream>>>(qkvc, relt, attnc);
      gemm_nt<1><<<mt*3,256,0,stream>>>(attnc, wp, projb, nullptr, outf, x, nullptr, c*Mc, 384,384,3);
    }
    ln2_k<<<12544,256,0,stream>>>(outf, n2w, n2b, B0);
    for (int c=0; c<nc; ++c){
      const u16* a1 = B0 + (size_t)c*Mc*384;
      float* oc = outf + (size_t)c*Mc*384;
      gemm_nt<2><<<mt*12,256,0,stream>>>(a1, w1, fc1b, fc1c, nullptr, nullptr, nullptr, 0, 1536,384,12);
      gemm_nt<3><<<mt*3 ,256,0,stream>>>(fc1c, w2, fc2b, nullptr, oc, nullptr, oc, 0, 384,1536,3);
    }
  }
}

// Round 16
// 430.446 us; speedup vs baseline: 1.0459x; 1.0268x over previous
//
#include <hip/hip_runtime.h>
#include <hip/hip_bf16.h>
#include <math.h>

typedef unsigned short u16;
typedef unsigned int u32;
typedef __attribute__((ext_vector_type(8))) short short8;
typedef __attribute__((ext_vector_type(4))) float f32x4;

__device__ __forceinline__ float b2f(u16 u){ u32 i = ((u32)u)<<16; float f; __builtin_memcpy(&f,&i,4); return f; }
__device__ __forceinline__ u16 f2b(float f){ u32 i; __builtin_memcpy(&i,&f,4); u32 r=(i+0x7FFFu+((i>>16)&1u))>>16; return (u16)r; }
__device__ __forceinline__ int region(int h){ return h<21?0:(h<25?1:2); }

// bijective XCD-aware swizzle (m204) — validated for 256-thread blocks
__device__ __forceinline__ int xswz(int bid, int nwg){
  int q = nwg >> 3, r = nwg & 7;
  int xcd = bid & 7, loc = bid >> 3;
  int base = (xcd < r) ? xcd*(q+1) : r*(q+1) + (xcd-r)*q;
  return base + loc;
}

// ---------------- all-weights f32 -> bf16 (one dispatch) ----------------
__global__ __launch_bounds__(256) void wcvt_all(
    const float* __restrict__ w0, u16* __restrict__ o0,
    const float* __restrict__ w1, u16* __restrict__ o1,
    const float* __restrict__ w2, u16* __restrict__ o2,
    const float* __restrict__ w3, u16* __restrict__ o3)
{
  int b = blockIdx.x;
  const float* in; u16* out; int ofs;
  if (b < 432){ in=w0; out=o0; ofs=b; }
  else if (b < 576){ in=w1; out=o1; ofs=b-432; }
  else if (b < 1152){ in=w2; out=o2; ofs=b-576; }
  else { in=w3; out=o3; ofs=b-1152; }
  int i = (ofs*256 + threadIdx.x)*4;
  f32x4 v = *(const f32x4*)(in + i);
  u16 o[4];
  #pragma unroll
  for (int e=0;e<4;e++) o[e] = f2b(v[e]);
  *(u32*)(out+i) = (u32)o[0] | ((u32)o[1]<<16);
  *(u32*)(out+i+2) = (u32)o[2] | ((u32)o[3]<<16);
}

// ---------------- LN1 (f32 in) + roll + window partition -> bf16 ----------------
__global__ __launch_bounds__(256) void ln1_win(const float* __restrict__ x,
    const float* __restrict__ w, const float* __restrict__ bb, u16* __restrict__ out)
{
  int lane = threadIdx.x & 63;
  int t = blockIdx.x*4 + (threadIdx.x>>6);
  int win = t/49, n = t - win*49;
  int b = win>>4, wi = win&15;
  int r = n/7, c = n - r*7;
  int oh = (wi>>2)*7 + r + 3; if (oh>=28) oh -= 28;
  int ow = (wi&3)*7 + c + 3; if (ow>=28) ow -= 28;
  size_t src = ((size_t)b*784 + oh*28 + ow)*384;
  float v[6];
  #pragma unroll
  for (int p=0;p<3;p++){
    float2 d = *(const float2*)(x + src + 2*lane + 128*p);
    v[2*p] = d.x; v[2*p+1] = d.y;
  }
  float s=0.f, sq=0.f;
  #pragma unroll
  for (int e=0;e<6;e++){ s+=v[e]; sq+=v[e]*v[e]; }
  #pragma unroll
  for (int off=32; off>=1; off>>=1){ s+=__shfl_xor(s,off); sq+=__shfl_xor(sq,off); }
  float mean = s*(1.f/384.f);
  float rstd = rsqrtf(sq*(1.f/384.f)-mean*mean + 1e-5f);
  size_t dst = (size_t)t*384;
  #pragma unroll
  for (int p=0;p<3;p++){
    int col = 2*lane+128*p;
    float2 wd = *(const float2*)(w+col), bd = *(const float2*)(bb+col);
    float y0 = (v[2*p]-mean)*rstd*wd.x + bd.x;
    float y1 = (v[2*p+1]-mean)*rstd*wd.y + bd.y;
    *(u32*)(out + dst + col) = (u32)f2b(y0) | ((u32)f2b(y1)<<16);
  }
}

// ---------------- LN2, f32 input (fallback path) ----------------
__global__ __launch_bounds__(256) void ln2_k(const float* __restrict__ x2,
    const float* __restrict__ w, const float* __restrict__ bb, u16* __restrict__ out)
{
  int lane = threadIdx.x & 63;
  int t = blockIdx.x*4 + (threadIdx.x>>6);
  size_t base = (size_t)t*384;
  float v[6];
  #pragma unroll
  for (int p=0;p<3;p++){
    float2 d = *(const float2*)(x2 + base + 2*lane + 128*p);
    v[2*p] = d.x; v[2*p+1] = d.y;
  }
  float s=0.f, sq=0.f;
  #pragma unroll
  for (int e=0;e<6;e++){ s+=v[e]; sq+=v[e]*v[e]; }
  #pragma unroll
  for (int off=32; off>=1; off>>=1){ s+=__shfl_xor(s,off); sq+=__shfl_xor(sq,off); }
  float mean = s*(1.f/384.f);
  float rstd = rsqrtf(sq*(1.f/384.f)-mean*mean + 1e-5f);
  #pragma unroll
  for (int p=0;p<3;p++){
    int col = 2*lane+128*p;
    float2 wd = *(const float2*)(w+col), bd = *(const float2*)(bb+col);
    float y0 = (v[2*p]-mean)*rstd*wd.x + bd.x;
    float y1 = (v[2*p+1]-mean)*rstd*wd.y + bd.y;
    *(u32*)(out + base + col) = (u32)f2b(y0) | ((u32)f2b(y1)<<16);
  }
}

// ---------------- LN2, bf16 input (main path) ----------------
__global__ __launch_bounds__(256) void ln2_b(const u16* __restrict__ x2b,
    const float* __restrict__ w, const float* __restrict__ bb, u16* __restrict__ out)
{
  int lane = threadIdx.x & 63;
  int t = blockIdx.x*4 + (threadIdx.x>>6);
  size_t base = (size_t)t*384;
  float v[6];
  #pragma unroll
  for (int p=0;p<3;p++){
    u32 d = *(const u32*)(x2b + base + 2*lane + 128*p);
    v[2*p] = b2f((u16)(d&0xFFFFu)); v[2*p+1] = b2f((u16)(d>>16));
  }
  float s=0.f, sq=0.f;
  #pragma unroll
  for (int e=0;e<6;e++){ s+=v[e]; sq+=v[e]*v[e]; }
  #pragma unroll
  for (int off=32; off>=1; off>>=1){ s+=__shfl_xor(s,off); sq+=__shfl_xor(sq,off); }
  float mean = s*(1.f/384.f);
  float rstd = rsqrtf(sq*(1.f/384.f)-mean*mean + 1e-5f);
  #pragma unroll
  for (int p=0;p<3;p++){
    int col = 2*lane+128*p;
    float2 wd = *(const float2*)(w+col), bd = *(const float2*)(bb+col);
    float y0 = (v[2*p]-mean)*rstd*wd.x + bd.x;
    float y1 = (v[2*p+1]-mean)*rstd*wd.y + bd.y;
    *(u32*)(out + base + col) = (u32)f2b(y0) | ((u32)f2b(y1)<<16);
  }
}

// ---------------- MFMA attention: 1 wave per (window, head) ----------------
// r15 base + XCD swizzle (window's 3 blocks share one L2) + interior-window mask skip.
__global__ __launch_bounds__(256) void attn_mfma(const u16* __restrict__ qkv,
    const float* __restrict__ table, u16* __restrict__ out)
{
  __shared__ __align__(16) u16 P[4][4096];
  __shared__ float bsh[4][224];
  int wv = threadIdx.x>>6, lane = threadIdx.x&63;
  int idx = xswz(blockIdx.x, gridDim.x)*4 + wv;
  int winl = idx/12, h = idx - winl*12;
  int wi = winl & 15;
  int g = lane>>4, q15 = lane&15;
  const float SCALE = 0.17677669529663687f;

  for (int e=lane; e<169; e+=64) bsh[wv][e] = table[e*12 + h];

  const u16* base = qkv + (size_t)winl*49*1152 + h*32;

  short8 qa[4], kb[4];
  #pragma unroll
  for (int t=0;t<4;t++){
    int tq = 16*t + q15; if (tq>48) tq = 48;
    qa[t] = *(const short8*)(base + (size_t)tq*1152 + g*8);
    kb[t] = *(const short8*)(base + (size_t)tq*1152 + 384 + g*8);
  }
  f32x4 zero = {0.f,0.f,0.f,0.f};
  f32x4 s[4][4];
  #pragma unroll
  for (int ti=0;ti<4;ti++){
    #pragma unroll
    for (int tj=0;tj<4;tj++) s[ti][tj] = zero;
  }
  __builtin_amdgcn_s_setprio(1);
  #pragma unroll
  for (int ti=0;ti<4;ti++){
    #pragma unroll
    for (int tj=0;tj<4;tj++)
      s[ti][tj] = __builtin_amdgcn_mfma_f32_16x16x32_bf16(qa[ti], kb[tj], s[ti][tj], 0,0,0);
  }
  __builtin_amdgcn_s_setprio(0);

  int hb7 = (wi>>2)*7, wb7 = (wi&3)*7;
  bool interior = (hb7 < 21) && (wb7 < 21);   // all region ids 0 -> mask == 0
  int yj[4], xj[4]; bool kjok[4];
  #pragma unroll
  for (int tj=0;tj<4;tj++){
    int kj = 16*tj + q15;
    kjok[tj] = (kj < 49);
    int y = (kj*37)>>8;
    yj[tj] = y; xj[tj] = kj - y*7;
  }
  if (interior){
    #pragma unroll
    for (int ti=0;ti<4;ti++){
      #pragma unroll
      for (int r=0;r<4;r++){
        int q = 16*ti + 4*g + r;
        int yi = (q*37)>>8, xi = q - yi*7;
        int bb0 = (yi+6)*13 + xi + 6;
        #pragma unroll
        for (int tj=0;tj<4;tj++){
          float v;
          if (kjok[tj]) v = s[ti][tj][r]*SCALE + bsh[wv][bb0 - yj[tj]*13 - xj[tj]];
          else          v = -1e30f;
          s[ti][tj][r] = v;
        }
      }
    }
  } else {
    int ridj[4];
    #pragma unroll
    for (int tj=0;tj<4;tj++)
      ridj[tj] = region(hb7+yj[tj])*3 + region(wb7+xj[tj]);
    #pragma unroll
    for (int ti=0;ti<4;ti++){
      #pragma unroll
      for (int r=0;r<4;r++){
        int q = 16*ti + 4*g + r;
        int yi = (q*37)>>8, xi = q - yi*7;
        int ridi = region(hb7+yi)*3 + region(wb7+xi);
        int bb0 = (yi+6)*13 + xi + 6;
        #pragma unroll
        for (int tj=0;tj<4;tj++){
          float v;
          if (kjok[tj]){
            float bias = bsh[wv][bb0 - yj[tj]*13 - xj[tj]];
            v = s[ti][tj][r]*SCALE + bias + ((ridi==ridj[tj]) ? 0.f : -100.f);
          } else v = -1e30f;
          s[ti][tj][r] = v;
        }
      }
    }
  }

  // softmax without max-shift (scores bounded; masked/padded exp -> 0)
  float inv[4][4];
  #pragma unroll
  for (int ti=0;ti<4;ti++){
    #pragma unroll
    for (int r=0;r<4;r++){
      float sum = 0.f;
      #pragma unroll
      for (int tj=0;tj<4;tj++){
        float e = __expf(s[ti][tj][r]);
        s[ti][tj][r] = e; sum += e;
      }
      sum += __shfl_xor(sum,1);
      sum += __shfl_xor(sum,2);
      sum += __shfl_xor(sum,4);
      sum += __shfl_xor(sum,8);
      inv[ti][r] = 1.f/sum;
    }
  }

  u16* Pw = P[wv];
  #pragma unroll
  for (int ti=0;ti<4;ti++){
    #pragma unroll
    for (int r=0;r<4;r++){
      int q = 16*ti + 4*g + r;
      int swz = (q&7)<<4;
      #pragma unroll
      for (int tj=0;tj<4;tj++){
        int kj = 16*tj + q15;
        *(u16*)((char*)Pw + ((q*128 + kj*2) ^ swz)) = f2b(s[ti][tj][r]);
      }
    }
  }
  __syncthreads();

  f32x4 o[4][2];
  #pragma unroll
  for (int ti=0;ti<4;ti++){ o[ti][0]=zero; o[ti][1]=zero; }
  #pragma unroll
  for (int kk=0;kk<2;kk++){
    short8 pa[4];
    #pragma unroll
    for (int ti=0;ti<4;ti++){
      int qq = 16*ti + q15;
      pa[ti] = *(const short8*)((char*)Pw + ((qq*128 + kk*64 + g*16) ^ ((qq&7)<<4)));
    }
    #pragma unroll
    for (int tn=0;tn<2;tn++){
      short8 vb;
      #pragma unroll
      for (int e=0;e<8;e++){
        int tok = kk*32 + g*8 + e; if (tok>48) tok = 48;
        vb[e] = *(const short*)(base + (size_t)tok*1152 + 768 + 16*tn + q15);
      }
      __builtin_amdgcn_s_setprio(1);
      #pragma unroll
      for (int ti=0;ti<4;ti++)
        o[ti][tn] = __builtin_amdgcn_mfma_f32_16x16x32_bf16(pa[ti], vb, o[ti][tn], 0,0,0);
      __builtin_amdgcn_s_setprio(0);
    }
  }

  // O -> dead P buffer (80B-stride rows), then coalesced 16B stores
  char* Ob = (char*)Pw;
  #pragma unroll
  for (int ti=0;ti<4;ti++){
    #pragma unroll
    for (int r=0;r<4;r++){
      int tok = 16*ti + 4*g + r;
      float iv = inv[ti][r];
      *(u16*)(Ob + tok*80 + q15*2)      = f2b(o[ti][0][r]*iv);
      *(u16*)(Ob + tok*80 + 32 + q15*2) = f2b(o[ti][1][r]*iv);
    }
  }
  {
    int tokb = lane>>2, d0 = (lane&3)*8;
    #pragma unroll
    for (int shot=0; shot<4; ++shot){
      int tok = shot*16 + tokb;
      if (tok < 49){
        short8 ov = *(const short8*)(Ob + tok*80 + d0*2);
        *(short8*)(out + ((size_t)(winl*49+tok))*384 + h*32 + d0) = ov;
      }
    }
  }
}

// ---------------- GEMM: 128x128, BK=32, 3-buf, 1 barrier/phase (round-10 proven) ----------------
// EPI: 0 bias->bf16 (coalesced) ; 1 proj f32-x2 (fallback) ; 2 bias+GELU->bf16 (coalesced)
//      3 fc2 f32-x2 (fallback) ; 4 proj -> bf16 x2b (outb) ; 5 fc2: dout = v + b2f(outb)
#define STAGE(b, koff) do { \
  u16* _la = SH + (b)*8192 + wid*512; \
  u16* _lb = SH + (b)*8192 + 4096 + wid*512; \
  __builtin_amdgcn_global_load_lds((const __attribute__((address_space(1))) void*)(gA0+(koff)), \
      (__attribute__((address_space(3))) void*)_la, 16,0,0); \
  __builtin_amdgcn_global_load_lds((const __attribute__((address_space(1))) void*)(gA1+(koff)), \
      (__attribute__((address_space(3))) void*)(_la+2048), 16,0,0); \
  __builtin_amdgcn_global_load_lds((const __attribute__((address_space(1))) void*)(gB0+(koff)), \
      (__attribute__((address_space(3))) void*)_lb, 16,0,0); \
  __builtin_amdgcn_global_load_lds((const __attribute__((address_space(1))) void*)(gB1+(koff)), \
      (__attribute__((address_space(3))) void*)(_lb+2048), 16,0,0); \
} while(0)

#define COMPUTE(b) do { \
  const u16* _Ab = SH + (b)*8192; \
  const u16* _Bb = _Ab + 4096; \
  short8 af[4], bf[4]; \
  _Pragma("unroll") \
  for (int t_=0;t_<4;t_++){ \
    af[t_] = *(const short8*)(_Ab + aidx[t_]); \
    bf[t_] = *(const short8*)(_Bb + bidx[t_]); } \
  __builtin_amdgcn_s_setprio(1); \
  _Pragma("unroll") \
  for (int mi=0;mi<4;mi++){ \
    _Pragma("unroll") \
    for (int ni=0;ni<4;ni++){ \
      acc[mi][ni] = __builtin_amdgcn_mfma_f32_16x16x32_bf16(af[mi], bf[ni], acc[mi][ni], 0,0,0); } } \
  __builtin_amdgcn_s_setprio(0); \
} while(0)

template<int EPI>
__global__ __launch_bounds__(256) void gemm_nt(
    const u16* __restrict__ A, const u16* __restrict__ W,
    const float* __restrict__ bias, u16* __restrict__ outb,
    float* __restrict__ x2, const float* __restrict__ xin,
    float* __restrict__ dout, int rowofs, int N, int K, int ntn)
{
  __shared__ __align__(16) u16 SH[24576];   // 48 KB: 3 bufs x (A 8KB + B 8KB)
  int bid = xswz(blockIdx.x, gridDim.x);
  int tm = bid / ntn, tn = bid - tm*ntn;
  int tid = threadIdx.x, lane = tid&63, wid = tid>>6;
  int wm = wid>>1, wn = wid&1;
  int fr = lane&15, fc = lane>>4;

  int s0 = wid*1024 + lane*16;
  int row0 = s0>>6;  int cl0 = ((s0>>4)&3) ^ ((row0>>1)&3);
  int s1b = s0 + 4096;
  int row1 = s1b>>6; int cl1 = ((s1b>>4)&3) ^ ((row1>>1)&3);
  const u16* gA0 = A + (size_t)(tm*128 + row0)*K + cl0*8;
  const u16* gA1 = A + (size_t)(tm*128 + row1)*K + cl1*8;
  const u16* gB0 = W + (size_t)(tn*128 + row0)*K + cl0*8;
  const u16* gB1 = W + (size_t)(tn*128 + row1)*K + cl1*8;

  f32x4 zero = {0.f,0.f,0.f,0.f};
  f32x4 acc[4][4];
  #pragma unroll
  for (int a=0;a<4;a++){
    #pragma unroll
    for (int b=0;b<4;b++) acc[a][b] = zero;
  }
  int aidx[4], bidx[4];
  #pragma unroll
  for (int t_=0;t_<4;t_++){
    int ra = wm*64 + t_*16 + fr;
    aidx[t_] = ra*32 + ((fc ^ ((ra>>1)&3))*8);
    int rb = wn*64 + t_*16 + fr;
    bidx[t_] = rb*32 + ((fc ^ ((rb>>1)&3))*8);
  }

  // 3-buf, single barrier per phase (round-10 schedule)
  int NT = K>>5;
  STAGE(0, 0);
  STAGE(1, 32);
  int b = 0;
  for (int t=0; t<NT; ++t){
    if (t < NT-1)  asm volatile("s_waitcnt vmcnt(4)" ::: "memory");
    else           asm volatile("s_waitcnt vmcnt(0)" ::: "memory");
    __builtin_amdgcn_s_barrier();
    __builtin_amdgcn_sched_barrier(0);
    int nb = b+2; if (nb>=3) nb-=3;
    if (t+2 < NT) STAGE(nb, (t+2)*32);
    COMPUTE(b);
    if (++b == 3) b = 0;
  }

  int colbase = tn*128 + wn*64;
  int rowbase = tm*128 + wm*64;

  if (EPI==0 || EPI==2){
    __builtin_amdgcn_s_barrier();
    u16* ep = SH + wid*4096;
    #pragma unroll
    for (int ni=0;ni<4;ni++){
      float bv = bias[colbase + ni*16 + fr];
      #pragma unroll
      for (int mi=0;mi<4;mi++){
        #pragma unroll
        for (int rr=0;rr<4;rr++){
          float v = acc[mi][ni][rr] + bv;
          if (EPI==2){
            float u2 = -1.5957691216057308f*(v + 0.044715f*v*v*v);
            v = v / (1.f + __expf(u2));
          }
          ep[(mi*16 + fc*4 + rr)*64 + ni*16 + fr] = f2b(v);
        }
      }
    }
    int half = lane>>5, c2 = (lane&31)*2;
    #pragma unroll
    for (int it=0; it<32; ++it){
      int lrow = it*2 + half;
      u32 v = *(const u32*)(ep + lrow*64 + c2);
      *(u32*)(outb + (size_t)(rowbase + lrow)*N + colbase + c2) = v;
    }
  } else {
    #pragma unroll
    for (int ni=0;ni<4;ni++){
      int col = colbase + ni*16 + fr;
      float bv = bias[col];
      #pragma unroll
      for (int mi=0;mi<4;mi++){
        #pragma unroll
        for (int rr=0;rr<4;rr++){
          int row = rowbase + mi*16 + fc*4 + rr;
          float v = acc[mi][ni][rr] + bv;
          if (EPI==1 || EPI==4){
            int grow = rowofs + row;
            int win = grow/49, n = grow - win*49;
            int bb = win>>4, wi = win&15;
            int hh = (wi>>2)*7 + n/7 + 3; if (hh>=28) hh -= 28;
            int ww = (wi&3)*7 + (n - (n/7)*7) + 3; if (ww>=28) ww -= 28;
            size_t ti = ((size_t)bb*784 + hh*28 + ww)*384 + col;
            if (EPI==1) x2[ti] = v + xin[ti];
            else        outb[ti] = f2b(v + xin[ti]);
          } else if (EPI==3){
            size_t ti = (size_t)row*N + col;
            dout[ti] = v + x2[ti];
          } else {  // EPI==5
            size_t ti = (size_t)row*N + col;
            dout[ti] = v + b2f(outb[ti]);
          }
        }
      }
    }
  }
}

extern "C" void kernel_launch(void* const* d_in, const int* in_sizes, int n_in,
                              void* d_out, int out_size, void* d_ws, size_t ws_size,
                              hipStream_t stream)
{
  const float* x     = (const float*)d_in[0];
  const float* n1w   = (const float*)d_in[2];
  const float* n1b   = (const float*)d_in[3];
  const float* qkvw  = (const float*)d_in[4];
  const float* qkvb  = (const float*)d_in[5];
  const float* relt  = (const float*)d_in[6];
  const float* projw = (const float*)d_in[7];
  const float* projb = (const float*)d_in[8];
  const float* n2w   = (const float*)d_in[9];
  const float* n2b   = (const float*)d_in[10];
  const float* fc1w  = (const float*)d_in[11];
  const float* fc1b  = (const float*)d_in[12];
  const float* fc2w  = (const float*)d_in[13];
  const float* fc2b  = (const float*)d_in[14];

  char* ws = (char*)d_ws;
  float* outf = (float*)d_out;

  if (ws_size >= 196214784){
    u16* B0    = (u16*)ws;
    u16* x2b   = (u16*)(ws + 38535168);
    u16* qkvc  = (u16*)(ws + 38535168);
    u16* fc1c  = (u16*)(ws + 77070336);
    u16* attnc = (u16*)(ws + 154140672);
    char* wb   = ws + 192675840;
    u16* wq = (u16*)(wb); u16* wp = (u16*)(wb + 884736);
    u16* w1 = (u16*)(wb + 1179648); u16* w2 = (u16*)(wb + 2359296);

    wcvt_all<<<1728,256,0,stream>>>(qkvw,wq, projw,wp, fc1w,w1, fc2w,w2);
    ln1_win<<<12544,256,0,stream>>>(x, n1w, n1b, B0);
    gemm_nt<0><<<392*9,256,0,stream>>>(B0, wq, qkvb, qkvc, nullptr, nullptr, nullptr, 0, 1152,384,9);
    attn_mfma<<<3072,256,0,stream>>>(qkvc, relt, attnc);
    gemm_nt<4><<<392*3,256,0,stream>>>(attnc, wp, projb, x2b, nullptr, x, nullptr, 0, 384,384,3);
    ln2_b<<<12544,256,0,stream>>>(x2b, n2w, n2b, B0);
    for (int c=0; c<2; ++c){
      const u16* a1 = B0 + (size_t)c*25088*384;
      gemm_nt<2><<<196*12,256,0,stream>>>(a1, w1, fc1b, fc1c, nullptr, nullptr, nullptr, 0, 1536,384,12);
      gemm_nt<5><<<196*3 ,256,0,stream>>>(fc1c, w2, fc2b, x2b + (size_t)c*25088*384, nullptr, nullptr,
                                          outf + (size_t)c*25088*384, 0, 384,1536,3);
    }
  } else {
    int nc = (ws_size >= 119144448) ? 2 : 4;
    int Mc = 50176/nc;
    u16* B0    = (u16*)ws;
    u16* qkvc  = (u16*)(ws + 38535168);
    u16* attnc = qkvc + (size_t)Mc*1152;
    u16* fc1c  = qkvc;
    char* wb   = ws + 38535168 + (size_t)Mc*3072;
    u16* wq = (u16*)(wb); u16* wp = (u16*)(wb + 884736);
    u16* w1 = (u16*)(wb + 1179648); u16* w2 = (u16*)(wb + 2359296);

    wcvt_all<<<1728,256,0,stream>>>(qkvw,wq, projw,wp, fc1w,w1, fc2w,w2);
    ln1_win<<<12544,256,0,stream>>>(x, n1w, n1b, B0);
    int mt = Mc/128;
    for (int c=0; c<nc; ++c){
      const u16* a0 = B0 + (size_t)c*Mc*384;
      gemm_nt<0><<<mt*9,256,0,stream>>>(a0, wq, qkvb, qkvc, nullptr, nullptr, nullptr, 0, 1152,384,9);
      attn_mfma<<<Mc/49*3,256,0,stream>>>(qkvc, relt, attnc);
      gemm_nt<1><<<mt*3,256,0,stream>>>(attnc, wp, projb, nullptr, outf, x, nullptr, c*Mc, 384,384,3);
    }
    ln2_k<<<12544,256,0,stream>>>(outf, n2w, n2b, B0);
    for (int c=0; c<nc; ++c){
      const u16* a1 = B0 + (size_t)c*Mc*384;
      float* oc = outf + (size_t)c*Mc*384;
      gemm_nt<2><<<mt*12,256,0,stream>>>(a1, w1, fc1b, fc1c, nullptr, nullptr, nullptr, 0, 1536,384,12);
      gemm_nt<3><<<mt*3 ,256,0,stream>>>(fc1c, w2, fc2b, nullptr, oc, nullptr, oc, 0, 384,1536,3);
    }
  }
}